// Round 1
// baseline (1555.773 us; speedup 1.0000x reference)
//
#include <hip/hip_runtime.h>
#include <hip/hip_cooperative_groups.h>
#include <math.h>

namespace cg = cooperative_groups;

#define N_ 2048
#define C_ 1000
#define D_ 768
#define K_ 5
#define CAP_ 128
#define MAXS_ 100
#define G5_ 512   // cooperative grid: 2 blocks/CU * 256 CU -> safely co-resident

// ---------------- K0: unary = -log(softmax(logits) + 1e-10) ----------------
__global__ __launch_bounds__(256) void k_unary(const float* __restrict__ logits,
                                               float* __restrict__ unary) {
    const int r = blockIdx.x, tid = threadIdx.x;
    const bool act = tid < 250;           // 250*4 = 1000 cols
    const int c0 = tid * 4;
    __shared__ float red[256];
    float4 l = act ? *(const float4*)(logits + (size_t)r * C_ + c0)
                   : make_float4(-INFINITY, -INFINITY, -INFINITY, -INFINITY);
    float m = fmaxf(fmaxf(l.x, l.y), fmaxf(l.z, l.w));
    red[tid] = m; __syncthreads();
    for (int s = 128; s > 0; s >>= 1) { if (tid < s) red[tid] = fmaxf(red[tid], red[tid + s]); __syncthreads(); }
    m = red[0]; __syncthreads();
    float e0 = 0, e1 = 0, e2 = 0, e3 = 0, sum = 0;
    if (act) { e0 = expf(l.x - m); e1 = expf(l.y - m); e2 = expf(l.z - m); e3 = expf(l.w - m); sum = e0 + e1 + e2 + e3; }
    red[tid] = sum; __syncthreads();
    for (int s = 128; s > 0; s >>= 1) { if (tid < s) red[tid] += red[tid + s]; __syncthreads(); }
    const float S = red[0]; __syncthreads();
    if (act) {
        float4 u;
        u.x = -logf(e0 / S + 1e-10f);
        u.y = -logf(e1 / S + 1e-10f);
        u.z = -logf(e2 / S + 1e-10f);
        u.w = -logf(e3 / S + 1e-10f);
        *(float4*)(unary + (size_t)r * C_ + c0) = u;
    }
}

// ---------------- K1: row-normalize feats ----------------
__global__ __launch_bounds__(256) void k_norm(const float* __restrict__ feats,
                                              float* __restrict__ fn) {
    const int r = blockIdx.x, tid = threadIdx.x;
    __shared__ float red[256];
    const float* row = feats + (size_t)r * D_;
    float ss = 0.f;
    for (int c = tid; c < D_; c += 256) { float v = row[c]; ss += v * v; }
    red[tid] = ss; __syncthreads();
    for (int s = 128; s > 0; s >>= 1) { if (tid < s) red[tid] += red[tid + s]; __syncthreads(); }
    const float n = sqrtf(red[0]); __syncthreads();
    for (int c = tid; c < D_; c += 256) fn[(size_t)r * D_ + c] = row[c] / n;
}

// ---------------- K2: sim = fn * fn^T (f32, 64x64 tile, 4x4 per thread) ----------------
__global__ __launch_bounds__(256) void k_gemm(const float* __restrict__ A,
                                              float* __restrict__ Csim) {
    __shared__ float As[16][65];
    __shared__ float Bs[16][65];
    const int tx = threadIdx.x % 16, ty = threadIdx.x / 16;
    const int m0 = blockIdx.y * 64, n0 = blockIdx.x * 64;
    float acc[4][4] = {};
    for (int k0 = 0; k0 < D_; k0 += 16) {
        #pragma unroll
        for (int l = 0; l < 4; l++) {
            int e = threadIdx.x + l * 256;   // 0..1023
            int mm = e >> 4, kk = e & 15;
            As[kk][mm] = A[(size_t)(m0 + mm) * D_ + k0 + kk];
            Bs[kk][mm] = A[(size_t)(n0 + mm) * D_ + k0 + kk];
        }
        __syncthreads();
        #pragma unroll
        for (int kk = 0; kk < 16; kk++) {
            float a[4], b[4];
            #pragma unroll
            for (int i = 0; i < 4; i++) a[i] = As[kk][ty * 4 + i];
            #pragma unroll
            for (int j = 0; j < 4; j++) b[j] = Bs[kk][tx * 4 + j];
            #pragma unroll
            for (int i = 0; i < 4; i++)
                #pragma unroll
                for (int j = 0; j < 4; j++) acc[i][j] += a[i] * b[j];
        }
        __syncthreads();
    }
    #pragma unroll
    for (int i = 0; i < 4; i++)
        #pragma unroll
        for (int j = 0; j < 4; j++)
            Csim[(size_t)(m0 + ty * 4 + i) * N_ + n0 + tx * 4 + j] = acc[i][j];
}

// ---------------- K3: per-row top-6 by (dist asc, idx asc); drop first (self) ----------------
__global__ __launch_bounds__(256) void k_topk(const float* __restrict__ sim,
                                              int* __restrict__ knn) {
    const int r = blockIdx.x, tid = threadIdx.x;
    float bd[6]; int bi[6];
    #pragma unroll
    for (int k = 0; k < 6; k++) { bd[k] = INFINITY; bi[k] = 0x7fffffff; }
    const float* srow = sim + (size_t)r * N_;
    for (int j = tid; j < N_; j += 256) {
        float s = srow[j];
        float d = sqrtf(fmaxf(2.f - 2.f * s, 0.f));   // matches ref clip+sqrt (tie semantics)
        if (d < bd[5] || (d == bd[5] && j < bi[5])) {
            int k = 5;
            while (k > 0 && (d < bd[k - 1] || (d == bd[k - 1] && j < bi[k - 1]))) {
                bd[k] = bd[k - 1]; bi[k] = bi[k - 1]; k--;
            }
            bd[k] = d; bi[k] = j;
        }
    }
    __shared__ float sd[256][6];
    __shared__ int   si[256][6];
    #pragma unroll
    for (int k = 0; k < 6; k++) { sd[tid][k] = bd[k]; si[tid][k] = bi[k]; }
    __syncthreads();
    for (int s = 128; s > 0; s >>= 1) {
        if (tid < s) {
            float md[6]; int mi[6];
            int p = 0, q = 0;
            #pragma unroll
            for (int k = 0; k < 6; k++) {
                float d1 = sd[tid][p], d2 = sd[tid + s][q];
                int i1 = si[tid][p], i2 = si[tid + s][q];
                bool take1 = (d1 < d2) || (d1 == d2 && i1 < i2);
                if (take1) { md[k] = d1; mi[k] = i1; p++; } else { md[k] = d2; mi[k] = i2; q++; }
            }
            #pragma unroll
            for (int k = 0; k < 6; k++) { sd[tid][k] = md[k]; si[tid][k] = mi[k]; }
        }
        __syncthreads();
    }
    if (tid < K_) knn[(size_t)r * K_ + tid] = si[0][1 + tid];  // drop col 0 (self), cols 1..5
}

// ---------------- K4: deterministic in-neighbor lists (no atomics) ----------------
__global__ __launch_bounds__(256) void k_inlist(const int* __restrict__ knn,
                                                int* __restrict__ indeg,
                                                int* __restrict__ inlist) {
    const int j = blockIdx.x * blockDim.x + threadIdx.x;
    if (j >= N_) return;
    int cnt = 0;
    for (int i = 0; i < N_; i++) {
        #pragma unroll
        for (int k = 0; k < K_; k++) {
            if (knn[i * K_ + k] == j && cnt < CAP_) { inlist[(size_t)j * CAP_ + cnt] = i; cnt++; }
        }
    }
    indeg[j] = cnt;
}

// ---------------- K5: cooperative LAME iteration loop ----------------
__global__ __launch_bounds__(256, 2) void k_lame(
    const float* __restrict__ unary, const int* __restrict__ knn,
    const int* __restrict__ indeg, const int* __restrict__ inlist,
    float* __restrict__ YA, float* __restrict__ YB,
    float* __restrict__ partials, float* __restrict__ out)
{
    cg::grid_group grid = cg::this_grid();
    const int tid = threadIdx.x;
    const bool act = tid < 250;
    const int c0 = tid * 4;
    __shared__ float red[256];
    __shared__ int nb[K_ + CAP_];
    __shared__ int ntot_s;

    // Y0 = softmax(-unary)
    for (int r = blockIdx.x; r < N_; r += gridDim.x) {
        float4 u = act ? *(const float4*)(unary + (size_t)r * C_ + c0) : make_float4(0, 0, 0, 0);
        float m = act ? fmaxf(fmaxf(-u.x, -u.y), fmaxf(-u.z, -u.w)) : -INFINITY;
        red[tid] = m; __syncthreads();
        for (int s = 128; s > 0; s >>= 1) { if (tid < s) red[tid] = fmaxf(red[tid], red[tid + s]); __syncthreads(); }
        m = red[0]; __syncthreads();
        float e0 = 0, e1 = 0, e2 = 0, e3 = 0, sum = 0;
        if (act) { e0 = expf(-u.x - m); e1 = expf(-u.y - m); e2 = expf(-u.z - m); e3 = expf(-u.w - m); sum = e0 + e1 + e2 + e3; }
        red[tid] = sum; __syncthreads();
        for (int s = 128; s > 0; s >>= 1) { if (tid < s) red[tid] += red[tid + s]; __syncthreads(); }
        const float S = red[0]; __syncthreads();
        if (act) {
            float4 y; y.x = e0 / S; y.y = e1 / S; y.z = e2 / S; y.w = e3 / S;
            *(float4*)(YA + (size_t)r * C_ + c0) = y;
        }
    }
    grid.sync();

    float oldE = INFINITY;
    const float* fin = YB;
    for (int it = 0; it < MAXS_; ++it) {
        const float* __restrict__ src = (it & 1) ? YB : YA;
        float* __restrict__ dst = (it & 1) ? YA : YB;
        for (int r = blockIdx.x; r < N_; r += gridDim.x) {
            if (tid == 0) ntot_s = K_ + indeg[r];
            if (tid < K_) nb[tid] = knn[r * K_ + tid];
            __syncthreads();
            const int ntot = ntot_s;
            if (tid < ntot - K_) nb[K_ + tid] = inlist[(size_t)r * CAP_ + tid];
            __syncthreads();
            float a0 = 0, a1 = 0, a2 = 0, a3 = 0;
            if (act) {
                for (int t = 0; t < ntot; t++) {
                    const float4 v = *(const float4*)(src + (size_t)nb[t] * C_ + c0);
                    a0 += v.x; a1 += v.y; a2 += v.z; a3 += v.w;
                }
            }
            float4 u = act ? *(const float4*)(unary + (size_t)r * C_ + c0) : make_float4(0, 0, 0, 0);
            const float z0 = 0.5f * a0 - u.x, z1 = 0.5f * a1 - u.y;
            const float z2 = 0.5f * a2 - u.z, z3 = 0.5f * a3 - u.w;
            float m = act ? fmaxf(fmaxf(z0, z1), fmaxf(z2, z3)) : -INFINITY;
            red[tid] = m; __syncthreads();
            for (int s = 128; s > 0; s >>= 1) { if (tid < s) red[tid] = fmaxf(red[tid], red[tid + s]); __syncthreads(); }
            m = red[0]; __syncthreads();
            float e0 = 0, e1 = 0, e2 = 0, e3 = 0, sum = 0;
            if (act) { e0 = expf(z0 - m); e1 = expf(z1 - m); e2 = expf(z2 - m); e3 = expf(z3 - m); sum = e0 + e1 + e2 + e3; }
            red[tid] = sum; __syncthreads();
            for (int s = 128; s > 0; s >>= 1) { if (tid < s) red[tid] += red[tid + s]; __syncthreads(); }
            const float S = red[0]; __syncthreads();
            float eloc = 0;
            if (act) {
                const float y0 = e0 / S, y1 = e1 / S, y2 = e2 / S, y3 = e3 / S;
                float4 y; y.x = y0; y.y = y1; y.z = y2; y.w = y3;
                *(float4*)(dst + (size_t)r * C_ + c0) = y;
                // unary*Y - pairwise*Y + Y*log(Y) == Y*(logY - z)  since z = pw - u
                eloc = y0 * (logf(fmaxf(y0, 1e-20f)) - z0)
                     + y1 * (logf(fmaxf(y1, 1e-20f)) - z1)
                     + y2 * (logf(fmaxf(y2, 1e-20f)) - z2)
                     + y3 * (logf(fmaxf(y3, 1e-20f)) - z3);
            }
            red[tid] = eloc; __syncthreads();
            for (int s = 128; s > 0; s >>= 1) { if (tid < s) red[tid] += red[tid + s]; __syncthreads(); }
            if (tid == 0) partials[(it & 1) * N_ + r] = red[0];
            __syncthreads();
        }
        grid.sync();
        // every block reduces all partials in the SAME fixed order -> bitwise-identical E
        const float* P = partials + (it & 1) * N_;
        float el = 0;
        #pragma unroll
        for (int k2 = 0; k2 < 8; k2++) el += P[tid * 8 + k2];
        red[tid] = el; __syncthreads();
        for (int s = 128; s > 0; s >>= 1) { if (tid < s) red[tid] += red[tid + s]; __syncthreads(); }
        const float E = red[0]; __syncthreads();
        const bool done = (it > 1) && (fabsf(E - oldE) <= 1e-8f * fabsf(oldE));
        oldE = E;
        fin = dst;
        if (done) break;   // uniform across all blocks (E bitwise identical)
    }
    for (int r = blockIdx.x; r < N_; r += gridDim.x) {
        if (act) *(float4*)(out + (size_t)r * C_ + c0) = *(const float4*)(fin + (size_t)r * C_ + c0);
    }
}

extern "C" void kernel_launch(void* const* d_in, const int* in_sizes, int n_in,
                              void* d_out, int out_size, void* d_ws, size_t ws_size,
                              hipStream_t stream) {
    const float* logits = (const float*)d_in[0];
    const float* feats  = (const float*)d_in[1];
    float* out = (float*)d_out;
    char* ws = (char*)d_ws;

    size_t off = 0;
    auto alloc = [&](size_t b) { size_t o = off; off += (b + 255) & ~(size_t)255; return o; };
    float* unary   = (float*)(ws + alloc((size_t)N_ * C_ * 4));
    float* fn      = (float*)(ws + alloc((size_t)N_ * D_ * 4));
    float* sim     = (float*)(ws + alloc((size_t)N_ * N_ * 4));   // reused as YA/YB after topk
    int*   knn     = (int*)(ws + alloc((size_t)N_ * K_ * 4));
    int*   indeg   = (int*)(ws + alloc((size_t)N_ * 4));
    int*   inlist  = (int*)(ws + alloc((size_t)N_ * CAP_ * 4));
    float* partials= (float*)(ws + alloc((size_t)2 * N_ * 4));
    if (off > ws_size) return;  // ws too small -> visible failure

    float* YA = sim;                       // N*C*4 = 8,192,000 B
    float* YB = sim + (size_t)N_ * C_;     // 2*N*C*4 = 16.38 MB <= N*N*4 = 16.78 MB

    k_unary <<<N_, 256, 0, stream>>>(logits, unary);
    k_norm  <<<N_, 256, 0, stream>>>(feats, fn);
    k_gemm  <<<dim3(N_ / 64, N_ / 64), 256, 0, stream>>>(fn, sim);
    k_topk  <<<N_, 256, 0, stream>>>(sim, knn);
    k_inlist<<<(N_ + 255) / 256, 256, 0, stream>>>(knn, indeg, inlist);

    const float* p_unary = unary;
    const int* p_knn = knn;
    const int* p_indeg = indeg;
    const int* p_inlist = inlist;
    float* p_YA = YA;
    float* p_YB = YB;
    float* p_part = partials;
    float* p_out = out;
    void* args[] = { &p_unary, &p_knn, &p_indeg, &p_inlist, &p_YA, &p_YB, &p_part, &p_out };
    hipLaunchCooperativeKernel((void*)k_lame, dim3(G5_), dim3(256), args, 0, stream);
}